// Round 11
// baseline (667.382 us; speedup 1.0000x reference)
//
#include <hip/hip_runtime.h>
#include <math.h>

#define T_ 64
#define N_ 40
#define D_ 4
#define H_ 256
#define R_ 64
#define E_ 1560
#define TE_ (T_*E_)
#define TN_ (T_*N_)

typedef unsigned short us;
typedef short short8 __attribute__((ext_vector_type(8)));
typedef float f32x4 __attribute__((ext_vector_type(4)));

__device__ __forceinline__ float elu_f(float x){ return x > 0.f ? x : (__expf(x) - 1.f); }
__device__ __forceinline__ float sig_f(float x){ return 1.f/(1.f+__expf(-x)); }
__device__ __forceinline__ float tanh_f(float x){ return 2.f/(1.f+__expf(-2.f*x)) - 1.f; }
__device__ __forceinline__ float dot4(float4 a, float4 b){ return a.x*b.x + a.y*b.y + a.z*b.z + a.w*b.w; }

__device__ __forceinline__ float bf2f(us u){ return __uint_as_float(((unsigned int)u) << 16); }
__device__ __forceinline__ us f2bf(float f){
    unsigned int u = __float_as_uint(f);
    u += 0x7FFFu + ((u >> 16) & 1u);
    return (us)(u >> 16);
}
__device__ __forceinline__ float4 ld4f(const float* p){ return *(const float4*)p; }
__device__ __forceinline__ float4 ld4f(const us* p){
    ushort4 v = *(const ushort4*)p;
    return make_float4(bf2f(v.x), bf2f(v.y), bf2f(v.z), bf2f(v.w));
}
__device__ __forceinline__ void st4f(float* p, float4 v){ *(float4*)p = v; }
__device__ __forceinline__ void st4f(us* p, float4 v){
    ushort4 o; o.x = f2bf(v.x); o.y = f2bf(v.y); o.z = f2bf(v.z); o.w = f2bf(v.w);
    *(ushort4*)p = o;
}

__device__ __forceinline__ void gld16(void* lds, const void* g){
    __builtin_amdgcn_global_load_lds((const __attribute__((address_space(1))) unsigned int*)g,
                                     (__attribute__((address_space(3))) unsigned int*)lds,
                                     16, 0, 0);
}

__device__ __forceinline__ void wsplit1(const float* W, us* hi, us* lo, int i){
    const float w = W[i];
    const us h = f2bf(w);
    hi[i] = h;
    lo[i] = f2bf(w - bf2f(h));
}

__global__ __launch_bounds__(256)
void wsplit_all(const float* __restrict__ s0, us* h0, us* l0,
                const float* __restrict__ s1, us* h1, us* l1,
                const float* __restrict__ s2, us* h2, us* l2,
                const float* __restrict__ s3, us* h3, us* l3,
                const float* __restrict__ s4, us* h4, us* l4,
                const float* __restrict__ s5, us* h5, us* l5,
                const float* __restrict__ s6, us* h6, us* l6,
                const float* __restrict__ s7, us* h7, us* l7)
{
    int i = blockIdx.x * 256 + threadIdx.x;
    if (i < 131072) { wsplit1(s0, h0, l0, i); return; } i -= 131072;
    if (i <  65536) { wsplit1(s1, h1, l1, i); return; } i -=  65536;
    if (i < 196608) { wsplit1(s2, h2, l2, i); return; } i -= 196608;
    if (i <  65536) { wsplit1(s3, h3, l3, i); return; } i -=  65536;
    if (i <  65536) { wsplit1(s4, h4, l4, i); return; } i -=  65536;
    if (i <  65536) { wsplit1(s5, h5, l5, i); return; } i -=  65536;
    if (i <  16384) { wsplit1(s6, h6, l6, i); return; } i -=  16384;
    wsplit1(s7, h7, l7, i);
}

__global__ __launch_bounds__(256)
void mlp1_kernel(const float* __restrict__ x,
                 const float* __restrict__ W1, const float* __restrict__ b1,
                 const float* __restrict__ W2, const float* __restrict__ b2,
                 us* __restrict__ hout)
{
    __shared__ float xs[8][4];
    __shared__ float h1[8][256];
    const int tid = threadIdx.x;
    const int r0  = blockIdx.x * 8;

    if (tid < 32) xs[tid >> 2][tid & 3] = x[r0 * 4 + tid];
    __syncthreads();

    const float4 w1 = *(const float4*)&W1[tid * 4];
    const float bb1 = b1[tid];
    #pragma unroll
    for (int row = 0; row < 8; ++row) {
        float v = bb1 + xs[row][0]*w1.x + xs[row][1]*w1.y + xs[row][2]*w1.z + xs[row][3]*w1.w;
        h1[row][tid] = elu_f(v);
    }
    __syncthreads();

    float acc[8];
    const float bb2 = b2[tid];
    #pragma unroll
    for (int row = 0; row < 8; ++row) acc[row] = bb2;
    const float* w2row = W2 + (size_t)tid * 256;
    for (int k4 = 0; k4 < 64; ++k4) {
        const float4 w = *(const float4*)&w2row[k4 * 4];
        #pragma unroll
        for (int row = 0; row < 8; ++row) {
            const float4 hh = *(const float4*)&h1[row][k4 * 4];
            acc[row] += dot4(hh, w);
        }
    }
    #pragma unroll
    for (int row = 0; row < 8; ++row)
        hout[(size_t)(r0 + row) * 256 + tid] = f2bf(elu_f(acc[row]));
}

// ---------------------------------------------------------------------------
// MFMA NT GEMM, double-buffered. Staging lane map: row=lane&15, chunk=lane>>4
// -> LDS lands chunk-major [chunk][row][16B] (lane*16 rule), so fragment
// ds_read_b128 at +ml*16 is 2-way-only (free); wave still covers the same 16
// full 64B lines per instruction (segment-based coalescer).
// DUAL (MODE 0): blockIdx.y in {2,3} uses second weight/bias/output set.
// ---------------------------------------------------------------------------
template<int MODE, bool DOELU>
__global__ __launch_bounds__(256)
void gemm_mfma(const us* __restrict__ A, const us* __restrict__ A2, const us* __restrict__ A3,
               const us* __restrict__ Whi, const us* __restrict__ Wlo,
               const float* __restrict__ bias1, const float* __restrict__ bias2,
               const int* __restrict__ send, const int* __restrict__ recv,
               us* __restrict__ C, int Kdim,
               const us* __restrict__ Whi2, const us* __restrict__ Wlo2,
               const float* __restrict__ bias1b, const float* __restrict__ bias2b,
               us* __restrict__ C2)
{
    __shared__ char smem[49152];

    const int tid  = threadIdx.x;
    const int lane = tid & 63;
    const int w    = tid >> 6;
    const int ml   = lane & 15;
    const int q    = lane >> 4;
    const int bx   = blockIdx.x;
    int by         = blockIdx.y;
    const int eh   = w >> 1;
    const int fh   = w & 1;

    if (MODE == 0 && C2 != nullptr && by >= 2) {
        Whi = Whi2; Wlo = Wlo2; bias1 = bias1b; bias2 = bias2b; C = C2; by -= 2;
    }

    // staging: lane covers (row = lane&15 of 16-row group, 16B chunk lane>>4)
    const int srow0 = w * 32 + ml;          // instr 0 rows
    const int srow1 = srow0 + 16;           // instr 1 rows
    const int cofs  = q * 8;                // element offset (8 bf16 = 16B)

    const int gr0 = bx * 128 + srow0, gr1 = bx * 128 + srow1;
    const us *pA0a=nullptr,*pA1a=nullptr,*pA2a=nullptr;
    const us *pA0b=nullptr,*pA1b=nullptr,*pA2b=nullptr;
    if (MODE == 0) {
        pA0a = A + (size_t)gr0 * Kdim;
        pA0b = A + (size_t)gr1 * Kdim;
    } else {
        const int t0 = gr0 / E_, e0 = gr0 - t0 * E_;
        const int t1 = gr1 / E_, e1 = gr1 - t1 * E_;
        pA0a = A  + ((size_t)(t0 * N_ + send[e0])) * H_;
        pA1a = A2 + ((size_t)(t0 * N_ + recv[e0])) * H_;
        pA0b = A  + ((size_t)(t1 * N_ + send[e1])) * H_;
        pA1b = A2 + ((size_t)(t1 * N_ + recv[e1])) * H_;
        if (MODE == 2) { pA2a = A3 + (size_t)gr0 * H_; pA2b = A3 + (size_t)gr1 * H_; }
    }
    const us* pWh0 = Whi + (size_t)(by * 128 + srow0) * Kdim;
    const us* pWh1 = Whi + (size_t)(by * 128 + srow1) * Kdim;
    const us* pWl0 = Wlo + (size_t)(by * 128 + srow0) * Kdim;
    const us* pWl1 = Wlo + (size_t)(by * 128 + srow1) * Kdim;

    f32x4 acc[4][4];
    #pragma unroll
    for (int i = 0; i < 4; ++i)
        #pragma unroll
        for (int j = 0; j < 4; ++j)
            acc[i][j] = (f32x4){0.f, 0.f, 0.f, 0.f};

    auto stage = [&](int k0, char* base) {
        const us *sa, *sb;
        if (MODE == 0) { sa = pA0a + k0; sb = pA0b + k0; }
        else if (MODE == 1) {
            sa = (k0 < 256) ? pA0a + k0 : pA1a + (k0 - 256);
            sb = (k0 < 256) ? pA0b + k0 : pA1b + (k0 - 256);
        } else {
            sa = (k0 < 256) ? pA0a + k0 : (k0 < 512) ? pA1a + (k0 - 256) : pA2a + (k0 - 512);
            sb = (k0 < 256) ? pA0b + k0 : (k0 < 512) ? pA1b + (k0 - 256) : pA2b + (k0 - 512);
        }
        gld16(base + w * 2048,                sa + cofs);
        gld16(base + w * 2048 + 1024,         sb + cofs);
        gld16(base + 8192  + w * 2048,        pWh0 + k0 + cofs);
        gld16(base + 8192  + w * 2048 + 1024, pWh1 + k0 + cofs);
        gld16(base + 16384 + w * 2048,        pWl0 + k0 + cofs);
        gld16(base + 16384 + w * 2048 + 1024, pWl1 + k0 + cofs);
    };

    stage(0, smem);
    const int nk = Kdim >> 5;
    for (int k = 0; k < nk; ++k) {
        char* cur = smem + (k & 1) * 24576;
        char* nxt = smem + ((k + 1) & 1) * 24576;
        __builtin_amdgcn_s_barrier();
        if (k + 1 < nk) {
            stage((k + 1) * 32, nxt);
            __builtin_amdgcn_s_waitcnt(0x3F76);  // vmcnt(6)
        } else {
            __builtin_amdgcn_s_waitcnt(0x3F70);  // vmcnt(0)
        }
        __builtin_amdgcn_s_barrier();

        // fragment LDS offset for row fr, chunk q: (fr>>4)*1024 + q*256 + (fr&15)*16
        short8 wh[4], wl[4], ef[4];
        #pragma unroll
        for (int mt = 0; mt < 4; ++mt) {
            const int blkOf = (fh * 4 + mt) * 1024 + q * 256 + ml * 16;
            wh[mt] = *(const short8*)(cur + 8192  + blkOf);
            wl[mt] = *(const short8*)(cur + 16384 + blkOf);
        }
        #pragma unroll
        for (int nt = 0; nt < 4; ++nt) {
            const int blkOf = (eh * 4 + nt) * 1024 + q * 256 + ml * 16;
            ef[nt] = *(const short8*)(cur + blkOf);
        }
        #pragma unroll
        for (int mt = 0; mt < 4; ++mt)
            #pragma unroll
            for (int nt = 0; nt < 4; ++nt) {
                acc[mt][nt] = __builtin_amdgcn_mfma_f32_16x16x32_bf16(wh[mt], ef[nt], acc[mt][nt], 0, 0, 0);
                acc[mt][nt] = __builtin_amdgcn_mfma_f32_16x16x32_bf16(wl[mt], ef[nt], acc[mt][nt], 0, 0, 0);
            }
    }

    #pragma unroll
    for (int mt = 0; mt < 4; ++mt) {
        const int colb = by * 128 + fh * 64 + mt * 16 + q * 4;
        float4 bb = *(const float4*)(bias1 + colb);
        if (bias2) {
            const float4 b2 = *(const float4*)(bias2 + colb);
            bb.x += b2.x; bb.y += b2.y; bb.z += b2.z; bb.w += b2.w;
        }
        #pragma unroll
        for (int nt = 0; nt < 4; ++nt) {
            const int row = bx * 128 + eh * 64 + nt * 16 + ml;
            float4 v;
            v.x = acc[mt][nt][0] + bb.x; v.y = acc[mt][nt][1] + bb.y;
            v.z = acc[mt][nt][2] + bb.z; v.w = acc[mt][nt][3] + bb.w;
            if (DOELU) { v.x = elu_f(v.x); v.y = elu_f(v.y); v.z = elu_f(v.z); v.w = elu_f(v.w); }
            ushort4 o; o.x = f2bf(v.x); o.y = f2bf(v.y); o.z = f2bf(v.z); o.w = f2bf(v.w);
            *(ushort4*)(C + (size_t)row * 256 + colb) = o;
        }
    }
}

template<bool DOELU, typename TA, typename TC>
__global__ __launch_bounds__(256)
void gemm_nt(const TA* __restrict__ A, const float* __restrict__ W,
             const float* __restrict__ bias1,
             TC* __restrict__ C, int M, int Kdim)
{
    __shared__ float As[16][64];
    __shared__ float Ws[16][64];

    const int tid = threadIdx.x;
    const int am  = tid >> 2;
    const int ak  = (tid & 3) * 4;
    const int gm  = blockIdx.x * 64 + am;

    const TA* aptr0 = A + (size_t)gm * Kdim;
    const float* wptr = W + (size_t)(blockIdx.y * 64 + am) * Kdim;

    const int tx = tid & 15, ty = tid >> 4;
    float acc[4][4] = {};

    for (int k0 = 0; k0 < Kdim; k0 += 16) {
        const float4 a4 = ld4f(aptr0 + k0 + ak);
        const float4 w4 = *(const float4*)(wptr + k0 + (tid & 3) * 4);

        __syncthreads();
        As[ak+0][am] = a4.x; As[ak+1][am] = a4.y; As[ak+2][am] = a4.z; As[ak+3][am] = a4.w;
        const int wk = (tid & 3) * 4;
        Ws[wk+0][am] = w4.x; Ws[wk+1][am] = w4.y; Ws[wk+2][am] = w4.z; Ws[wk+3][am] = w4.w;
        __syncthreads();

        #pragma unroll
        for (int kq = 0; kq < 16; ++kq) {
            const float4 av = *(const float4*)&As[kq][ty * 4];
            const float4 wv = *(const float4*)&Ws[kq][tx * 4];
            const float a_[4] = {av.x, av.y, av.z, av.w};
            const float w_[4] = {wv.x, wv.y, wv.z, wv.w};
            #pragma unroll
            for (int i = 0; i < 4; ++i)
                #pragma unroll
                for (int j = 0; j < 4; ++j)
                    acc[i][j] += a_[i] * w_[j];
        }
    }

    const int gn = blockIdx.y * 64 + tx * 4;
    const float4 bb = *(const float4*)&bias1[gn];
    #pragma unroll
    for (int i = 0; i < 4; ++i) {
        const int row = blockIdx.x * 64 + ty * 4 + i;
        float4 o;
        o.x = acc[i][0] + bb.x; o.y = acc[i][1] + bb.y;
        o.z = acc[i][2] + bb.z; o.w = acc[i][3] + bb.w;
        if (DOELU) { o.x = elu_f(o.x); o.y = elu_f(o.y); o.z = elu_f(o.z); o.w = elu_f(o.w); }
        st4f(C + (size_t)row * 256 + gn, o);
    }
}

// edge2node aggregate, analytic edge list (bit-identical summation order).
__global__ __launch_bounds__(256)
void aggregate_kernel(const us* __restrict__ eSkip, const int* __restrict__ recv,
                      float* __restrict__ nAgg)
{
    const int t = blockIdx.x / N_;
    const int j = blockIdx.x - t * N_;
    const int c = threadIdx.x;
    const us* basep = eSkip + (size_t)t * E_ * H_ + c;
    float acc = 0.f;
    #pragma unroll
    for (int s = 0; s < N_; ++s) {
        if (s == j) continue;
        const int e = s * (N_ - 1) + (j < s ? j : j - 1);
        acc += bf2f(basep[(size_t)e * H_]);
    }
    nAgg[(size_t)blockIdx.x * H_ + c] = acc;
}

// ---------------------------------------------------------------------------
// LSTM recurrence v4: wave = r-quarter. Wave w computes all 4 gate types for
// r in [16w,16w+16): A rows = mt*64 + w*16 + ml. Lane (ml,q)'s 4 accs are then
// (i,f,g,o) for edge ml, r = w*16+q*4..+3 -> pointwise fully in registers.
// Ping-pong h planes -> ONE barrier per step. Same per-(edge,gate) arithmetic
// and order as v3 -> bit-identical output.
// ---------------------------------------------------------------------------
__global__ __launch_bounds__(256)
void lstm_mfma(const us* __restrict__ Gf, const us* __restrict__ Gr,
               const us* __restrict__ fWhhH, const us* __restrict__ fWhhL,
               const us* __restrict__ rWhhH, const us* __restrict__ rWhhL,
               float* __restrict__ hsF, float* __restrict__ hsR)
{
    const int NBD = (E_ + 15) / 16;
    const bool revd = (int)blockIdx.x >= NBD;
    const int blk = revd ? (int)blockIdx.x - NBD : (int)blockIdx.x;
    const int e0 = blk * 16;
    const us* G  = revd ? Gr : Gf;
    const us* WH = revd ? rWhhH : fWhhH;
    const us* WL = revd ? rWhhL : fWhhL;
    float* hs    = revd ? hsR : hsF;

    const int tid  = threadIdx.x;
    const int lane = tid & 63;
    const int w    = tid >> 6;
    const int ml   = lane & 15;
    const int q    = lane >> 4;

    __shared__ us hHi[2][16][72];
    __shared__ us hLo[2][16][72];

    // Whh A-frags: row g = mt*64 + w*16 + ml, k = ks*32 + q*8
    short8 wfh[4][2], wfl[4][2];
    #pragma unroll
    for (int mt = 0; mt < 4; ++mt) {
        const int row = mt * 64 + w * 16 + ml;
        #pragma unroll
        for (int ks = 0; ks < 2; ++ks) {
            wfh[mt][ks] = *(const short8*)(WH + (size_t)row * 64 + ks * 32 + q * 8);
            wfl[mt][ks] = *(const short8*)(WL + (size_t)row * 64 + ks * 32 + q * 8);
        }
    }

    for (int i = tid; i < 16 * 72; i += 256) { (&hHi[0][0][0])[i] = 0; (&hLo[0][0][0])[i] = 0; }

    const int eMF = min(e0 + ml, E_ - 1);
    const bool wr = (e0 + ml) < E_;
    const int gOfs = w * 16 + q * 4;   // r offset within the 64-gate group
    float4 cst = make_float4(0.f, 0.f, 0.f, 0.f);

    ushort4 gcur[4], gnxt[4];
    {
        const int tt0 = revd ? (T_ - 1) : 0;
        const us* gp = G + ((size_t)tt0 * E_ + eMF) * 256 + gOfs;
        #pragma unroll
        for (int mt = 0; mt < 4; ++mt) gcur[mt] = *(const ushort4*)(gp + mt * 64);
    }
    __syncthreads();

    for (int s = 0; s < T_; ++s) {
        const int tt = revd ? (T_ - 1 - s) : s;
        {
            const int sn = (s + 1 < T_) ? s + 1 : s;
            const int tn = revd ? (T_ - 1 - sn) : sn;
            const us* gp = G + ((size_t)tn * E_ + eMF) * 256 + gOfs;
            #pragma unroll
            for (int mt = 0; mt < 4; ++mt) gnxt[mt] = *(const ushort4*)(gp + mt * 64);
        }
        const int rb = s & 1, wb = rb ^ 1;
        short8 bh[2], bl[2];
        #pragma unroll
        for (int ks = 0; ks < 2; ++ks) {
            bh[ks] = *(const short8*)(&hHi[rb][ml][ks * 32 + q * 8]);
            bl[ks] = *(const short8*)(&hLo[rb][ml][ks * 32 + q * 8]);
        }
        f32x4 acc[4];
        #pragma unroll
        for (int mt = 0; mt < 4; ++mt) {
            acc[mt][0] = bf2f(gcur[mt].x); acc[mt][1] = bf2f(gcur[mt].y);
            acc[mt][2] = bf2f(gcur[mt].z); acc[mt][3] = bf2f(gcur[mt].w);
            #pragma unroll
            for (int ks = 0; ks < 2; ++ks) {
                acc[mt] = __builtin_amdgcn_mfma_f32_16x16x32_bf16(wfh[mt][ks], bh[ks], acc[mt], 0, 0, 0);
                acc[mt] = __builtin_amdgcn_mfma_f32_16x16x32_bf16(wfh[mt][ks], bl[ks], acc[mt], 0, 0, 0);
                acc[mt] = __builtin_amdgcn_mfma_f32_16x16x32_bf16(wfl[mt][ks], bh[ks], acc[mt], 0, 0, 0);
            }
        }
        // pointwise in registers: acc[0]=i, acc[1]=f, acc[2]=g, acc[3]=o
        float4 hv;
        cst.x = sig_f(acc[1][0])*cst.x + sig_f(acc[0][0])*tanh_f(acc[2][0]); hv.x = sig_f(acc[3][0])*tanh_f(cst.x);
        cst.y = sig_f(acc[1][1])*cst.y + sig_f(acc[0][1])*tanh_f(acc[2][1]); hv.y = sig_f(acc[3][1])*tanh_f(cst.y);
        cst.z = sig_f(acc[1][2])*cst.z + sig_f(acc[0][2])*tanh_f(acc[2][2]); hv.z = sig_f(acc[3][2])*tanh_f(cst.z);
        cst.w = sig_f(acc[1][3])*cst.w + sig_f(acc[0][3])*tanh_f(acc[2][3]); hv.w = sig_f(acc[3][3])*tanh_f(cst.w);
        ushort4 hh4, hl4;
        hh4.x = f2bf(hv.x); hl4.x = f2bf(hv.x - bf2f(hh4.x));
        hh4.y = f2bf(hv.y); hl4.y = f2bf(hv.y - bf2f(hh4.y));
        hh4.z = f2bf(hv.z); hl4.z = f2bf(hv.z - bf2f(hh4.z));
        hh4.w = f2bf(hv.w); hl4.w = f2bf(hv.w - bf2f(hh4.w));
        *(ushort4*)(&hHi[wb][ml][gOfs]) = hh4;
        *(ushort4*)(&hLo[wb][ml][gOfs]) = hl4;
        if (wr)
            *(float4*)(&hs[((size_t)tt * E_ + e0 + ml) * 64 + gOfs]) = hv;
        __syncthreads();
        #pragma unroll
        for (int mt = 0; mt < 4; ++mt) gcur[mt] = gnxt[mt];
    }
}

__global__ __launch_bounds__(256)
void out_kernel(const float* __restrict__ hsF, const float* __restrict__ hsR,
                const float* __restrict__ priW, const float* __restrict__ prib,
                const float* __restrict__ encW, const float* __restrict__ encb,
                float* __restrict__ out)
{
    const int idx = blockIdx.x * 256 + threadIdx.x;
    const float* f = hsF + (size_t)idx * 64;
    const float* r = hsR + (size_t)idx * 64;
    float p0 = prib[0], p1 = prib[1], q0 = encb[0], q1 = encb[1];
    #pragma unroll
    for (int k4 = 0; k4 < 16; ++k4) {
        const float4 fv = *(const float4*)(f + k4 * 4);
        const float4 rv = *(const float4*)(r + k4 * 4);
        p0 += dot4(fv, *(const float4*)(priW + k4 * 4));
        p1 += dot4(fv, *(const float4*)(priW + 64 + k4 * 4));
        q0 += dot4(fv, *(const float4*)(encW + k4 * 4))
            + dot4(rv, *(const float4*)(encW + 64 + k4 * 4));
        q1 += dot4(fv, *(const float4*)(encW + 128 + k4 * 4))
            + dot4(rv, *(const float4*)(encW + 192 + k4 * 4));
    }
    float4 o; o.x = p0; o.y = p1; o.z = q0; o.w = q1;
    *(float4*)(out + (size_t)idx * 4) = o;
}

extern "C" void kernel_launch(void* const* d_in, const int* in_sizes, int n_in,
                              void* d_out, int out_size, void* d_ws, size_t ws_size,
                              hipStream_t stream)
{
    const float* x    = (const float*)d_in[0];
    const int*   send = (const int*)d_in[2];
    const int*   recv = (const int*)d_in[3];
    const float* m1W1 = (const float*)d_in[4];  const float* m1b1 = (const float*)d_in[5];
    const float* m1W2 = (const float*)d_in[6];  const float* m1b2 = (const float*)d_in[7];
    const float* m2W1 = (const float*)d_in[8];  const float* m2b1 = (const float*)d_in[9];
    const float* m2W2 = (const float*)d_in[10]; const float* m2b2 = (const float*)d_in[11];
    const float* m3W1 = (const float*)d_in[12]; const float* m3b1 = (const float*)d_in[13];
    const float* m3W2 = (const float*)d_in[14]; const float* m3b2 = (const float*)d_in[15];
    const float* m4W1 = (const float*)d_in[16]; const float* m4b1 = (const float*)d_in[17];
    const float* m4W2 = (const float*)d_in[18]; const float* m4b2 = (const float*)d_in[19];
    const float* fWih = (const float*)d_in[20]; const float* fWhh = (const float*)d_in[21];
    const float* fbih = (const float*)d_in[22]; const float* fbhh = (const float*)d_in[23];
    const float* rWih = (const float*)d_in[24]; const float* rWhh = (const float*)d_in[25];
    const float* rbih = (const float*)d_in[26]; const float* rbhh = (const float*)d_in[27];
    const float* encW = (const float*)d_in[28]; const float* encb = (const float*)d_in[29];
    const float* priW = (const float*)d_in[30]; const float* prib = (const float*)d_in[31];

    const size_t SZN  = (size_t)TN_ * H_;
    const size_t SZE  = (size_t)TE_ * H_;
    float* n_agg = (float*)d_ws;
    float* m3t   = n_agg + SZN;
    us* h16      = (us*)(m3t + SZN);
    us* n3       = h16 + SZN;
    us* w2aH = n3  + SZN;          us* w2aL = w2aH + 256*512;
    us* w2bH = w2aL + 256*512;     us* w2bL = w2bH + 256*256;
    us* w4aH = w2bL + 256*256;     us* w4aL = w4aH + 256*768;
    us* w4bH = w4aL + 256*768;     us* w4bL = w4bH + 256*256;
    us* wfiH = w4bL + 256*256;     us* wfiL = wfiH + 256*256;
    us* wriH = wfiL + 256*256;     us* wriL = wriH + 256*256;
    us* whfH = wriL + 256*256;     us* whfL = whfH + 256*64;
    us* whrH = whfL + 256*64;      us* whrL = whrH + 256*64;
    us* bufA16 = whrL + 256*64;
    us* bufB16 = bufA16 + SZE;
    us* bufC16 = bufB16 + SZE;
    float* hsF = (float*)bufC16;
    float* hsR = hsF + (size_t)TE_ * R_;
    const size_t needed = ((size_t)(bufC16 + SZE) - (size_t)d_ws);
    if (ws_size < needed) return;

    const dim3 gMF(TE_ / 128, 2), gMF4(TE_ / 128, 4), gN(TN_ / 64, 4);
    const us* z = nullptr; const float* zf = nullptr; us* zo = nullptr;

    wsplit_all<<<2432, 256, 0, stream>>>(m2W1, w2aH, w2aL, m2W2, w2bH, w2bL,
                                         m4W1, w4aH, w4aL, m4W2, w4bH, w4bL,
                                         fWih, wfiH, wfiL, rWih, wriH, wriL,
                                         fWhh, whfH, whfL, rWhh, whrH, whrL);

    mlp1_kernel<<<TN_ / 8, 256, 0, stream>>>(x, m1W1, m1b1, m1W2, m1b2, h16);
    gemm_mfma<1, true><<<gMF, 256, 0, stream>>>(h16, h16, nullptr, w2aH, w2aL, m2b1, nullptr, send, recv, bufA16, 512, z, z, zf, zf, zo);
    gemm_mfma<0, true><<<gMF, 256, 0, stream>>>(bufA16, nullptr, nullptr, w2bH, w2bL, m2b2, nullptr, send, recv, bufB16, 256, z, z, zf, zf, zo);
    aggregate_kernel<<<TN_, 256, 0, stream>>>(bufB16, recv, n_agg);
    gemm_nt<true, float, float><<<gN, 256, 0, stream>>>(n_agg, m3W1, m3b1, m3t, TN_, 256);
    gemm_nt<true, float, us><<<gN, 256, 0, stream>>>(m3t, m3W2, m3b2, n3, TN_, 256);
    gemm_mfma<2, true><<<gMF, 256, 0, stream>>>(n3, n3, bufB16, w4aH, w4aL, m4b1, nullptr, send, recv, bufA16, 768, z, z, zf, zf, zo);
    gemm_mfma<0, true><<<gMF, 256, 0, stream>>>(bufA16, nullptr, nullptr, w4bH, w4bL, m4b2, nullptr, send, recv, bufC16, 256, z, z, zf, zf, zo);
    gemm_mfma<0, false><<<gMF4, 256, 0, stream>>>(bufC16, nullptr, nullptr, wfiH, wfiL, fbih, fbhh, send, recv, bufA16, 256,
                                                  wriH, wriL, rbih, rbhh, bufB16);
    lstm_mfma<<<2 * ((E_ + 15) / 16), 256, 0, stream>>>(bufA16, bufB16, whfH, whfL, whrH, whrL, hsF, hsR);
    out_kernel<<<TE_ / 256, 256, 0, stream>>>(hsF, hsR, priW, prib, encW, encb, (float*)d_out);
}

// Round 12
// 583.493 us; speedup vs baseline: 1.1438x; 1.1438x over previous
//
#include <hip/hip_runtime.h>
#include <math.h>

#define T_ 64
#define N_ 40
#define D_ 4
#define H_ 256
#define R_ 64
#define E_ 1560
#define TE_ (T_*E_)
#define TN_ (T_*N_)

typedef unsigned short us;
typedef short short8 __attribute__((ext_vector_type(8)));
typedef float f32x4 __attribute__((ext_vector_type(4)));

__device__ __forceinline__ float elu_f(float x){ return x > 0.f ? x : (__expf(x) - 1.f); }
__device__ __forceinline__ float sig_f(float x){ return 1.f/(1.f+__expf(-x)); }
__device__ __forceinline__ float tanh_f(float x){ return 2.f/(1.f+__expf(-2.f*x)) - 1.f; }
__device__ __forceinline__ float dot4(float4 a, float4 b){ return a.x*b.x + a.y*b.y + a.z*b.z + a.w*b.w; }

__device__ __forceinline__ float bf2f(us u){ return __uint_as_float(((unsigned int)u) << 16); }
__device__ __forceinline__ us f2bf(float f){
    unsigned int u = __float_as_uint(f);
    u += 0x7FFFu + ((u >> 16) & 1u);
    return (us)(u >> 16);
}
__device__ __forceinline__ float4 ld4f(const float* p){ return *(const float4*)p; }
__device__ __forceinline__ float4 ld4f(const us* p){
    ushort4 v = *(const ushort4*)p;
    return make_float4(bf2f(v.x), bf2f(v.y), bf2f(v.z), bf2f(v.w));
}
__device__ __forceinline__ void st4f(float* p, float4 v){ *(float4*)p = v; }
__device__ __forceinline__ void st4f(us* p, float4 v){
    ushort4 o; o.x = f2bf(v.x); o.y = f2bf(v.y); o.z = f2bf(v.z); o.w = f2bf(v.w);
    *(ushort4*)p = o;
}

__device__ __forceinline__ void gld16(void* lds, const void* g){
    __builtin_amdgcn_global_load_lds((const __attribute__((address_space(1))) unsigned int*)g,
                                     (__attribute__((address_space(3))) unsigned int*)lds,
                                     16, 0, 0);
}

__device__ __forceinline__ void wsplit1(const float* W, us* hi, us* lo, int i){
    const float w = W[i];
    const us h = f2bf(w);
    hi[i] = h;
    lo[i] = f2bf(w - bf2f(h));
}

__global__ __launch_bounds__(256)
void wsplit_all(const float* __restrict__ s0, us* h0, us* l0,
                const float* __restrict__ s1, us* h1, us* l1,
                const float* __restrict__ s2, us* h2, us* l2,
                const float* __restrict__ s3, us* h3, us* l3,
                const float* __restrict__ s4, us* h4, us* l4,
                const float* __restrict__ s5, us* h5, us* l5,
                const float* __restrict__ s6, us* h6, us* l6,
                const float* __restrict__ s7, us* h7, us* l7)
{
    int i = blockIdx.x * 256 + threadIdx.x;
    if (i < 131072) { wsplit1(s0, h0, l0, i); return; } i -= 131072;
    if (i <  65536) { wsplit1(s1, h1, l1, i); return; } i -=  65536;
    if (i < 196608) { wsplit1(s2, h2, l2, i); return; } i -= 196608;
    if (i <  65536) { wsplit1(s3, h3, l3, i); return; } i -=  65536;
    if (i <  65536) { wsplit1(s4, h4, l4, i); return; } i -=  65536;
    if (i <  65536) { wsplit1(s5, h5, l5, i); return; } i -=  65536;
    if (i <  16384) { wsplit1(s6, h6, l6, i); return; } i -=  16384;
    wsplit1(s7, h7, l7, i);
}

__global__ __launch_bounds__(256)
void mlp1_kernel(const float* __restrict__ x,
                 const float* __restrict__ W1, const float* __restrict__ b1,
                 const float* __restrict__ W2, const float* __restrict__ b2,
                 us* __restrict__ hout)
{
    __shared__ float xs[8][4];
    __shared__ float h1[8][256];
    const int tid = threadIdx.x;
    const int r0  = blockIdx.x * 8;

    if (tid < 32) xs[tid >> 2][tid & 3] = x[r0 * 4 + tid];
    __syncthreads();

    const float4 w1 = *(const float4*)&W1[tid * 4];
    const float bb1 = b1[tid];
    #pragma unroll
    for (int row = 0; row < 8; ++row) {
        float v = bb1 + xs[row][0]*w1.x + xs[row][1]*w1.y + xs[row][2]*w1.z + xs[row][3]*w1.w;
        h1[row][tid] = elu_f(v);
    }
    __syncthreads();

    float acc[8];
    const float bb2 = b2[tid];
    #pragma unroll
    for (int row = 0; row < 8; ++row) acc[row] = bb2;
    const float* w2row = W2 + (size_t)tid * 256;
    for (int k4 = 0; k4 < 64; ++k4) {
        const float4 w = *(const float4*)&w2row[k4 * 4];
        #pragma unroll
        for (int row = 0; row < 8; ++row) {
            const float4 hh = *(const float4*)&h1[row][k4 * 4];
            acc[row] += dot4(hh, w);
        }
    }
    #pragma unroll
    for (int row = 0; row < 8; ++row)
        hout[(size_t)(r0 + row) * 256 + tid] = f2bf(elu_f(acc[row]));
}

// ---------------------------------------------------------------------------
// MFMA NT GEMM, double-buffered. Staging: lane = row*4 + cs (coalesced, 4
// lanes cover one 64B line) but the lane loads global chunk c = cs ^ ((row>>1)&3)
// (XOR swizzle; permutation within the 64B segment keeps coalescing). Global
// chunk q of row r then sits at LDS r*64 + (q^((r>>1)&3))*16 -> fragment
// ds_read_b128 is 2-way-only (free). Round-10 coalescing + round-11 no-conflict.
// DUAL (MODE 0): blockIdx.y in {2,3} uses second weight/bias/output set.
// ---------------------------------------------------------------------------
template<int MODE, bool DOELU>
__global__ __launch_bounds__(256)
void gemm_mfma(const us* __restrict__ A, const us* __restrict__ A2, const us* __restrict__ A3,
               const us* __restrict__ Whi, const us* __restrict__ Wlo,
               const float* __restrict__ bias1, const float* __restrict__ bias2,
               const int* __restrict__ send, const int* __restrict__ recv,
               us* __restrict__ C, int Kdim,
               const us* __restrict__ Whi2, const us* __restrict__ Wlo2,
               const float* __restrict__ bias1b, const float* __restrict__ bias2b,
               us* __restrict__ C2)
{
    __shared__ char smem[49152];

    const int tid  = threadIdx.x;
    const int lane = tid & 63;
    const int w    = tid >> 6;
    const int ml   = lane & 15;
    const int q    = lane >> 4;
    const int bx   = blockIdx.x;
    int by         = blockIdx.y;
    const int eh   = w >> 1;
    const int fh   = w & 1;

    if (MODE == 0 && C2 != nullptr && by >= 2) {
        Whi = Whi2; Wlo = Wlo2; bias1 = bias1b; bias2 = bias2b; C = C2; by -= 2;
    }

    // staging: r = lane>>2 (row in 16-group), cs = lane&3 (stored chunk);
    // global chunk loaded = cs ^ ((r>>1)&3)
    const int srow0 = w * 32 + (lane >> 2);
    const int srow1 = srow0 + 16;
    const int cofs  = (((lane & 3) ^ ((lane >> 3) & 3)) * 8);

    const int gr0 = bx * 128 + srow0, gr1 = bx * 128 + srow1;
    const us *pA0a=nullptr,*pA1a=nullptr,*pA2a=nullptr;
    const us *pA0b=nullptr,*pA1b=nullptr,*pA2b=nullptr;
    if (MODE == 0) {
        pA0a = A + (size_t)gr0 * Kdim;
        pA0b = A + (size_t)gr1 * Kdim;
    } else {
        const int t0 = gr0 / E_, e0 = gr0 - t0 * E_;
        const int t1 = gr1 / E_, e1 = gr1 - t1 * E_;
        pA0a = A  + ((size_t)(t0 * N_ + send[e0])) * H_;
        pA1a = A2 + ((size_t)(t0 * N_ + recv[e0])) * H_;
        pA0b = A  + ((size_t)(t1 * N_ + send[e1])) * H_;
        pA1b = A2 + ((size_t)(t1 * N_ + recv[e1])) * H_;
        if (MODE == 2) { pA2a = A3 + (size_t)gr0 * H_; pA2b = A3 + (size_t)gr1 * H_; }
    }
    const us* pWh0 = Whi + (size_t)(by * 128 + srow0) * Kdim;
    const us* pWh1 = Whi + (size_t)(by * 128 + srow1) * Kdim;
    const us* pWl0 = Wlo + (size_t)(by * 128 + srow0) * Kdim;
    const us* pWl1 = Wlo + (size_t)(by * 128 + srow1) * Kdim;

    f32x4 acc[4][4];
    #pragma unroll
    for (int i = 0; i < 4; ++i)
        #pragma unroll
        for (int j = 0; j < 4; ++j)
            acc[i][j] = (f32x4){0.f, 0.f, 0.f, 0.f};

    auto stage = [&](int k0, char* base) {
        const us *sa, *sb;
        if (MODE == 0) { sa = pA0a + k0; sb = pA0b + k0; }
        else if (MODE == 1) {
            sa = (k0 < 256) ? pA0a + k0 : pA1a + (k0 - 256);
            sb = (k0 < 256) ? pA0b + k0 : pA1b + (k0 - 256);
        } else {
            sa = (k0 < 256) ? pA0a + k0 : (k0 < 512) ? pA1a + (k0 - 256) : pA2a + (k0 - 512);
            sb = (k0 < 256) ? pA0b + k0 : (k0 < 512) ? pA1b + (k0 - 256) : pA2b + (k0 - 512);
        }
        gld16(base + w * 2048,                sa + cofs);
        gld16(base + w * 2048 + 1024,         sb + cofs);
        gld16(base + 8192  + w * 2048,        pWh0 + k0 + cofs);
        gld16(base + 8192  + w * 2048 + 1024, pWh1 + k0 + cofs);
        gld16(base + 16384 + w * 2048,        pWl0 + k0 + cofs);
        gld16(base + 16384 + w * 2048 + 1024, pWl1 + k0 + cofs);
    };

    // fragment LDS offset for row fr (0..127), global chunk q:
    //   (fr>>4)*1024 + (fr&15)*64 + (q ^ ((fr>>1)&3))*16   [fr&15 == ml here]
    const int qs16 = (q ^ ((ml >> 1) & 3)) * 16;

    stage(0, smem);
    const int nk = Kdim >> 5;
    for (int k = 0; k < nk; ++k) {
        char* cur = smem + (k & 1) * 24576;
        char* nxt = smem + ((k + 1) & 1) * 24576;
        __builtin_amdgcn_s_barrier();
        if (k + 1 < nk) {
            stage((k + 1) * 32, nxt);
            __builtin_amdgcn_s_waitcnt(0x3F76);  // vmcnt(6)
        } else {
            __builtin_amdgcn_s_waitcnt(0x3F70);  // vmcnt(0)
        }
        __builtin_amdgcn_s_barrier();

        short8 wh[4], wl[4], ef[4];
        #pragma unroll
        for (int mt = 0; mt < 4; ++mt) {
            const int blkOf = (fh * 4 + mt) * 1024 + ml * 64 + qs16;
            wh[mt] = *(const short8*)(cur + 8192  + blkOf);
            wl[mt] = *(const short8*)(cur + 16384 + blkOf);
        }
        #pragma unroll
        for (int nt = 0; nt < 4; ++nt) {
            const int blkOf = (eh * 4 + nt) * 1024 + ml * 64 + qs16;
            ef[nt] = *(const short8*)(cur + blkOf);
        }
        #pragma unroll
        for (int mt = 0; mt < 4; ++mt)
            #pragma unroll
            for (int nt = 0; nt < 4; ++nt) {
                acc[mt][nt] = __builtin_amdgcn_mfma_f32_16x16x32_bf16(wh[mt], ef[nt], acc[mt][nt], 0, 0, 0);
                acc[mt][nt] = __builtin_amdgcn_mfma_f32_16x16x32_bf16(wl[mt], ef[nt], acc[mt][nt], 0, 0, 0);
            }
    }

    #pragma unroll
    for (int mt = 0; mt < 4; ++mt) {
        const int colb = by * 128 + fh * 64 + mt * 16 + q * 4;
        float4 bb = *(const float4*)(bias1 + colb);
        if (bias2) {
            const float4 b2 = *(const float4*)(bias2 + colb);
            bb.x += b2.x; bb.y += b2.y; bb.z += b2.z; bb.w += b2.w;
        }
        #pragma unroll
        for (int nt = 0; nt < 4; ++nt) {
            const int row = bx * 128 + eh * 64 + nt * 16 + ml;
            float4 v;
            v.x = acc[mt][nt][0] + bb.x; v.y = acc[mt][nt][1] + bb.y;
            v.z = acc[mt][nt][2] + bb.z; v.w = acc[mt][nt][3] + bb.w;
            if (DOELU) { v.x = elu_f(v.x); v.y = elu_f(v.y); v.z = elu_f(v.z); v.w = elu_f(v.w); }
            ushort4 o; o.x = f2bf(v.x); o.y = f2bf(v.y); o.z = f2bf(v.z); o.w = f2bf(v.w);
            *(ushort4*)(C + (size_t)row * 256 + colb) = o;
        }
    }
}

template<bool DOELU, typename TA, typename TC>
__global__ __launch_bounds__(256)
void gemm_nt(const TA* __restrict__ A, const float* __restrict__ W,
             const float* __restrict__ bias1,
             TC* __restrict__ C, int M, int Kdim)
{
    __shared__ float As[16][64];
    __shared__ float Ws[16][64];

    const int tid = threadIdx.x;
    const int am  = tid >> 2;
    const int ak  = (tid & 3) * 4;
    const int gm  = blockIdx.x * 64 + am;

    const TA* aptr0 = A + (size_t)gm * Kdim;
    const float* wptr = W + (size_t)(blockIdx.y * 64 + am) * Kdim;

    const int tx = tid & 15, ty = tid >> 4;
    float acc[4][4] = {};

    for (int k0 = 0; k0 < Kdim; k0 += 16) {
        const float4 a4 = ld4f(aptr0 + k0 + ak);
        const float4 w4 = *(const float4*)(wptr + k0 + (tid & 3) * 4);

        __syncthreads();
        As[ak+0][am] = a4.x; As[ak+1][am] = a4.y; As[ak+2][am] = a4.z; As[ak+3][am] = a4.w;
        const int wk = (tid & 3) * 4;
        Ws[wk+0][am] = w4.x; Ws[wk+1][am] = w4.y; Ws[wk+2][am] = w4.z; Ws[wk+3][am] = w4.w;
        __syncthreads();

        #pragma unroll
        for (int kq = 0; kq < 16; ++kq) {
            const float4 av = *(const float4*)&As[kq][ty * 4];
            const float4 wv = *(const float4*)&Ws[kq][tx * 4];
            const float a_[4] = {av.x, av.y, av.z, av.w};
            const float w_[4] = {wv.x, wv.y, wv.z, wv.w};
            #pragma unroll
            for (int i = 0; i < 4; ++i)
                #pragma unroll
                for (int j = 0; j < 4; ++j)
                    acc[i][j] += a_[i] * w_[j];
        }
    }

    const int gn = blockIdx.y * 64 + tx * 4;
    const float4 bb = *(const float4*)&bias1[gn];
    #pragma unroll
    for (int i = 0; i < 4; ++i) {
        const int row = blockIdx.x * 64 + ty * 4 + i;
        float4 o;
        o.x = acc[i][0] + bb.x; o.y = acc[i][1] + bb.y;
        o.z = acc[i][2] + bb.z; o.w = acc[i][3] + bb.w;
        if (DOELU) { o.x = elu_f(o.x); o.y = elu_f(o.y); o.z = elu_f(o.z); o.w = elu_f(o.w); }
        st4f(C + (size_t)row * 256 + gn, o);
    }
}

// edge2node aggregate, analytic edge list (bit-identical summation order).
__global__ __launch_bounds__(256)
void aggregate_kernel(const us* __restrict__ eSkip, const int* __restrict__ recv,
                      float* __restrict__ nAgg)
{
    const int t = blockIdx.x / N_;
    const int j = blockIdx.x - t * N_;
    const int c = threadIdx.x;
    const us* basep = eSkip + (size_t)t * E_ * H_ + c;
    float acc = 0.f;
    #pragma unroll
    for (int s = 0; s < N_; ++s) {
        if (s == j) continue;
        const int e = s * (N_ - 1) + (j < s ? j : j - 1);
        acc += bf2f(basep[(size_t)e * H_]);
    }
    nAgg[(size_t)blockIdx.x * H_ + c] = acc;
}

// LSTM recurrence v4 (round 11): wave = r-quarter, pointwise in registers,
// ping-pong h planes, one barrier/step. Bit-identical arithmetic.
__global__ __launch_bounds__(256)
void lstm_mfma(const us* __restrict__ Gf, const us* __restrict__ Gr,
               const us* __restrict__ fWhhH, const us* __restrict__ fWhhL,
               const us* __restrict__ rWhhH, const us* __restrict__ rWhhL,
               float* __restrict__ hsF, float* __restrict__ hsR)
{
    const int NBD = (E_ + 15) / 16;
    const bool revd = (int)blockIdx.x >= NBD;
    const int blk = revd ? (int)blockIdx.x - NBD : (int)blockIdx.x;
    const int e0 = blk * 16;
    const us* G  = revd ? Gr : Gf;
    const us* WH = revd ? rWhhH : fWhhH;
    const us* WL = revd ? rWhhL : fWhhL;
    float* hs    = revd ? hsR : hsF;

    const int tid  = threadIdx.x;
    const int lane = tid & 63;
    const int w    = tid >> 6;
    const int ml   = lane & 15;
    const int q    = lane >> 4;

    __shared__ us hHi[2][16][72];
    __shared__ us hLo[2][16][72];

    short8 wfh[4][2], wfl[4][2];
    #pragma unroll
    for (int mt = 0; mt < 4; ++mt) {
        const int row = mt * 64 + w * 16 + ml;
        #pragma unroll
        for (int ks = 0; ks < 2; ++ks) {
            wfh[mt][ks] = *(const short8*)(WH + (size_t)row * 64 + ks * 32 + q * 8);
            wfl[mt][ks] = *(const short8*)(WL + (size_t)row * 64 + ks * 32 + q * 8);
        }
    }

    for (int i = tid; i < 16 * 72; i += 256) { (&hHi[0][0][0])[i] = 0; (&hLo[0][0][0])[i] = 0; }

    const int eMF = min(e0 + ml, E_ - 1);
    const bool wr = (e0 + ml) < E_;
    const int gOfs = w * 16 + q * 4;
    float4 cst = make_float4(0.f, 0.f, 0.f, 0.f);

    ushort4 gcur[4], gnxt[4];
    {
        const int tt0 = revd ? (T_ - 1) : 0;
        const us* gp = G + ((size_t)tt0 * E_ + eMF) * 256 + gOfs;
        #pragma unroll
        for (int mt = 0; mt < 4; ++mt) gcur[mt] = *(const ushort4*)(gp + mt * 64);
    }
    __syncthreads();

    for (int s = 0; s < T_; ++s) {
        const int tt = revd ? (T_ - 1 - s) : s;
        {
            const int sn = (s + 1 < T_) ? s + 1 : s;
            const int tn = revd ? (T_ - 1 - sn) : sn;
            const us* gp = G + ((size_t)tn * E_ + eMF) * 256 + gOfs;
            #pragma unroll
            for (int mt = 0; mt < 4; ++mt) gnxt[mt] = *(const ushort4*)(gp + mt * 64);
        }
        const int rb = s & 1, wb = rb ^ 1;
        short8 bh[2], bl[2];
        #pragma unroll
        for (int ks = 0; ks < 2; ++ks) {
            bh[ks] = *(const short8*)(&hHi[rb][ml][ks * 32 + q * 8]);
            bl[ks] = *(const short8*)(&hLo[rb][ml][ks * 32 + q * 8]);
        }
        f32x4 acc[4];
        #pragma unroll
        for (int mt = 0; mt < 4; ++mt) {
            acc[mt][0] = bf2f(gcur[mt].x); acc[mt][1] = bf2f(gcur[mt].y);
            acc[mt][2] = bf2f(gcur[mt].z); acc[mt][3] = bf2f(gcur[mt].w);
            #pragma unroll
            for (int ks = 0; ks < 2; ++ks) {
                acc[mt] = __builtin_amdgcn_mfma_f32_16x16x32_bf16(wfh[mt][ks], bh[ks], acc[mt], 0, 0, 0);
                acc[mt] = __builtin_amdgcn_mfma_f32_16x16x32_bf16(wfh[mt][ks], bl[ks], acc[mt], 0, 0, 0);
                acc[mt] = __builtin_amdgcn_mfma_f32_16x16x32_bf16(wfl[mt][ks], bh[ks], acc[mt], 0, 0, 0);
            }
        }
        float4 hv;
        cst.x = sig_f(acc[1][0])*cst.x + sig_f(acc[0][0])*tanh_f(acc[2][0]); hv.x = sig_f(acc[3][0])*tanh_f(cst.x);
        cst.y = sig_f(acc[1][1])*cst.y + sig_f(acc[0][1])*tanh_f(acc[2][1]); hv.y = sig_f(acc[3][1])*tanh_f(cst.y);
        cst.z = sig_f(acc[1][2])*cst.z + sig_f(acc[0][2])*tanh_f(acc[2][2]); hv.z = sig_f(acc[3][2])*tanh_f(cst.z);
        cst.w = sig_f(acc[1][3])*cst.w + sig_f(acc[0][3])*tanh_f(acc[2][3]); hv.w = sig_f(acc[3][3])*tanh_f(cst.w);
        ushort4 hh4, hl4;
        hh4.x = f2bf(hv.x); hl4.x = f2bf(hv.x - bf2f(hh4.x));
        hh4.y = f2bf(hv.y); hl4.y = f2bf(hv.y - bf2f(hh4.y));
        hh4.z = f2bf(hv.z); hl4.z = f2bf(hv.z - bf2f(hh4.z));
        hh4.w = f2bf(hv.w); hl4.w = f2bf(hv.w - bf2f(hh4.w));
        *(ushort4*)(&hHi[wb][ml][gOfs]) = hh4;
        *(ushort4*)(&hLo[wb][ml][gOfs]) = hl4;
        if (wr)
            *(float4*)(&hs[((size_t)tt * E_ + e0 + ml) * 64 + gOfs]) = hv;
        __syncthreads();
        #pragma unroll
        for (int mt = 0; mt < 4; ++mt) gcur[mt] = gnxt[mt];
    }
}

__global__ __launch_bounds__(256)
void out_kernel(const float* __restrict__ hsF, const float* __restrict__ hsR,
                const float* __restrict__ priW, const float* __restrict__ prib,
                const float* __restrict__ encW, const float* __restrict__ encb,
                float* __restrict__ out)
{
    const int idx = blockIdx.x * 256 + threadIdx.x;
    const float* f = hsF + (size_t)idx * 64;
    const float* r = hsR + (size_t)idx * 64;
    float p0 = prib[0], p1 = prib[1], q0 = encb[0], q1 = encb[1];
    #pragma unroll
    for (int k4 = 0; k4 < 16; ++k4) {
        const float4 fv = *(const float4*)(f + k4 * 4);
        const float4 rv = *(const float4*)(r + k4 * 4);
        p0 += dot4(fv, *(const float4*)(priW + k4 * 4));
        p1 += dot4(fv, *(const float4*)(priW + 64 + k4 * 4));
        q0 += dot4(fv, *(const float4*)(encW + k4 * 4))
            + dot4(rv, *(const float4*)(encW + 64 + k4 * 4));
        q1 += dot4(fv, *(const float4*)(encW + 128 + k4 * 4))
            + dot4(rv, *(const float4*)(encW + 192 + k4 * 4));
    }
    float4 o; o.x = p0; o.y = p1; o.z = q0; o.w = q1;
    *(float4*)(out + (size_t)idx * 4) = o;
}

extern "C" void kernel_launch(void* const* d_in, const int* in_sizes, int n_in,
                              void* d_out, int out_size, void* d_ws, size_t ws_size,
                              hipStream_t stream)
{
    const float* x    = (const float*)d_in[0];
    const int*   send = (const int*)d_in[2];
    const int*   recv = (const int*)d_in[3];
    const float* m1W1 = (const float*)d_in[4];  const float* m1b1 = (const float*)d_in[5];
    const float* m1W2 = (const float*)d_in[6];  const float* m1b2 = (const float*)d_in[7];
    const float* m2W1 = (const float*)d_in[8];  const float* m2b1 = (const float*)d_in[9];
    const float* m2W2 = (const float*)d_in[10]; const float* m2b2 = (const float*)d_in[11];
    const float* m3W1 = (const float*)d_in[12]; const float* m3b1 = (const float*)d_in[13];
    const float* m3W2 = (const float*)d_in[14]; const float* m3b2 = (const float*)d_in[15];
    const float* m4W1 = (const float*)d_in[16]; const float* m4b1 = (const float*)d_in[17];
    const float* m4W2 = (const float*)d_in[18]; const float* m4b2 = (const float*)d_in[19];
    const float* fWih = (const float*)d_in[20]; const float* fWhh = (const float*)d_in[21];
    const float* fbih = (const float*)d_in[22]; const float* fbhh = (const float*)d_in[23];
    const float* rWih = (const float*)d_in[24]; const float* rWhh = (const float*)d_in[25];
    const float* rbih = (const float*)d_in[26]; const float* rbhh = (const float*)d_in[27];
    const float* encW = (const float*)d_in[28]; const float* encb = (const float*)d_in[29];
    const float* priW = (const float*)d_in[30]; const float* prib = (const float*)d_in[31];

    const size_t SZN  = (size_t)TN_ * H_;
    const size_t SZE  = (size_t)TE_ * H_;
    float* n_agg = (float*)d_ws;
    float* m3t   = n_agg + SZN;
    us* h16      = (us*)(m3t + SZN);
    us* n3       = h16 + SZN;
    us* w2aH = n3  + SZN;          us* w2aL = w2aH + 256*512;
    us* w2bH = w2aL + 256*512;     us* w2bL = w2bH + 256*256;
    us* w4aH = w2bL + 256*256;     us* w4aL = w4aH + 256*768;
    us* w4bH = w4aL + 256*768;     us* w4bL = w4bH + 256*256;
    us* wfiH = w4bL + 256*256;     us* wfiL = wfiH + 256*256;
    us* wriH = wfiL + 256*256;     us* wriL = wriH + 256*256;
    us* whfH = wriL + 256*256;     us* whfL = whfH + 256*64;
    us* whrH = whfL + 256*64;      us* whrL = whrH + 256*64;
    us* bufA16 = whrL + 256*64;
    us* bufB16 = bufA16 + SZE;
    us* bufC16 = bufB16 + SZE;
    float* hsF = (float*)bufC16;
    float* hsR = hsF + (size_t)TE_ * R_;
    const size_t needed = ((size_t)(bufC16 + SZE) - (size_t)d_ws);
    if (ws_size < needed) return;

    const dim3 gMF(TE_ / 128, 2), gMF4(TE_ / 128, 4), gN(TN_ / 64, 4);
    const us* z = nullptr; const float* zf = nullptr; us* zo = nullptr;

    wsplit_all<<<2432, 256, 0, stream>>>(m2W1, w2aH, w2aL, m2W2, w2bH, w2bL,
                                         m4W1, w4aH, w4aL, m4W2, w4bH, w4bL,
                                         fWih, wfiH, wfiL, rWih, wriH, wriL,
                                         fWhh, whfH, whfL, rWhh, whrH, whrL);

    mlp1_kernel<<<TN_ / 8, 256, 0, stream>>>(x, m1W1, m1b1, m1W2, m1b2, h16);
    gemm_mfma<1, true><<<gMF, 256, 0, stream>>>(h16, h16, nullptr, w2aH, w2aL, m2b1, nullptr, send, recv, bufA16, 512, z, z, zf, zf, zo);
    gemm_mfma<0, true><<<gMF, 256, 0, stream>>>(bufA16, nullptr, nullptr, w2bH, w2bL, m2b2, nullptr, send, recv, bufB16, 256, z, z, zf, zf, zo);
    aggregate_kernel<<<TN_, 256, 0, stream>>>(bufB16, recv, n_agg);
    gemm_nt<true, float, float><<<gN, 256, 0, stream>>>(n_agg, m3W1, m3b1, m3t, TN_, 256);
    gemm_nt<true, float, us><<<gN, 256, 0, stream>>>(m3t, m3W2, m3b2, n3, TN_, 256);
    gemm_mfma<2, true><<<gMF, 256, 0, stream>>>(n3, n3, bufB16, w4aH, w4aL, m4b1, nullptr, send, recv, bufA16, 768, z, z, zf, zf, zo);
    gemm_mfma<0, true><<<gMF, 256, 0, stream>>>(bufA16, nullptr, nullptr, w4bH, w4bL, m4b2, nullptr, send, recv, bufC16, 256, z, z, zf, zf, zo);
    gemm_mfma<0, false><<<gMF4, 256, 0, stream>>>(bufC16, nullptr, nullptr, wfiH, wfiL, fbih, fbhh, send, recv, bufA16, 256,
                                                  wriH, wriL, rbih, rbhh, bufB16);
    lstm_mfma<<<2 * ((E_ + 15) / 16), 256, 0, stream>>>(bufA16, bufB16, whfH, whfL, whrH, whrL, hsF, hsR);
    out_kernel<<<TE_ / 256, 256, 0, stream>>>(hsF, hsR, priW, prib, encW, encb, (float*)d_out);
}